// Round 7
// baseline (575.851 us; speedup 1.0000x reference)
//
#include <hip/hip_runtime.h>
#include <hip/hip_cooperative_groups.h>
#include <math.h>

namespace cg = cooperative_groups;

#define NEGF (-1e30f)

// ws float offsets
#define P_OFF    0u          // spanmax partials: 192*8*768 = 1179648
#define ENT_OFF  1179648u    // ent (B,3,D) = 147456
#define EA_OFF   1327104u    // e state A
#define EB_OFF   1474560u    // e state B
#define SP_OFF   1622016u    // s-partials [8][192][5] = 7680
#define PRED_OFF 1629696u    // pred strip partials [64][4][5] = 1280
// total ~6.5 MB

__device__ __forceinline__ float sigmoidf_(float x){ return 1.0f/(1.0f+expf(-x)); }

__global__ __launch_bounds__(512, 1) void k_mega(
    const float* __restrict__ enc, const int* __restrict__ ent_pos,
    const float* __restrict__ ArW, const float* __restrict__ Arb,
    const float* __restrict__ VrW1, const float* __restrict__ Vrb1,
    const float* __restrict__ VrW2, const float* __restrict__ Vrb2,
    const float* __restrict__ gW, const float* __restrict__ gb,
    const float* __restrict__ pW1, const float* __restrict__ pb1,
    const float* __restrict__ pW2, const float* __restrict__ pb2,
    const float* __restrict__ projW, const float* __restrict__ projb,
    float* __restrict__ out, float* __restrict__ ws)
{
    cg::grid_group grid = cg::this_grid();
    __shared__ float smem[22048];   // 88 KB, max over phases
    const int blk = blockIdx.x;     // 0..255
    const int t = threadIdx.x;      // 0..511

    // ================= P1: span-max partials (1536 tasks, 6/block) =========
    {
        int grp = t / 192;          // 0,1 active; 2 idle tail
        int lane = t - grp*192;
        if (grp < 2){
            #pragma unroll
            for (int i=0; i<3; ++i){
                int v = blk*6 + grp*3 + i;
                int bi = v >> 3, c = v & 7;
                int b = bi/3;
                int st = ent_pos[bi*2+0], en = ent_pos[bi*2+1];
                int r0 = max(st, c*64), r1 = min(en, c*64+63);
                float4 m = make_float4(NEGF,NEGF,NEGF,NEGF);
                const float4* e4 = (const float4*)enc + (size_t)b*512*192 + lane;
                int r = r0;
                for (; r+3<=r1; r+=4){
                    float4 v0 = e4[(size_t)(r  )*192];
                    float4 v1 = e4[(size_t)(r+1)*192];
                    float4 v2 = e4[(size_t)(r+2)*192];
                    float4 v3 = e4[(size_t)(r+3)*192];
                    m.x=fmaxf(m.x,fmaxf(fmaxf(v0.x,v1.x),fmaxf(v2.x,v3.x)));
                    m.y=fmaxf(m.y,fmaxf(fmaxf(v0.y,v1.y),fmaxf(v2.y,v3.y)));
                    m.z=fmaxf(m.z,fmaxf(fmaxf(v0.z,v1.z),fmaxf(v2.z,v3.z)));
                    m.w=fmaxf(m.w,fmaxf(fmaxf(v0.w,v1.w),fmaxf(v2.w,v3.w)));
                }
                for (; r<=r1; ++r){
                    float4 v0 = e4[(size_t)r*192];
                    m.x=fmaxf(m.x,v0.x); m.y=fmaxf(m.y,v0.y);
                    m.z=fmaxf(m.z,v0.z); m.w=fmaxf(m.w,v0.w);
                }
                ((float4*)(ws+P_OFF))[(bi*8+c)*192 + lane] = m;
            }
        }
    }
    grid.sync();

    // ================= P2: reduce partials -> ent, eA, ent_score ===========
    if (blk < 192){
        int bi = blk;
        float* red = smem;
        float local = 0.f;
        if (t < 192){
            float4 m = make_float4(NEGF,NEGF,NEGF,NEGF);
            const float4* p4 = (const float4*)(ws+P_OFF);
            for (int c=0;c<8;++c){
                float4 v = p4[(bi*8+c)*192+t];
                m.x=fmaxf(m.x,v.x); m.y=fmaxf(m.y,v.y); m.z=fmaxf(m.z,v.z); m.w=fmaxf(m.w,v.w);
            }
            ((float4*)(ws+ENT_OFF))[bi*192+t] = m;
            ((float4*)(ws+EA_OFF))[bi*192+t] = m;
            float4 w = ((const float4*)projW)[t];
            local = m.x*w.x + m.y*w.y + m.z*w.z + m.w*w.w;
        }
        if (t < 256) red[t] = (t<192) ? local : 0.f;
        __syncthreads();
        for (int off=128; off>0; off>>=1){ if (t<off) red[t]+=red[t+off]; __syncthreads(); }
        if (t==0) out[320 + bi] = sigmoidf_(red[0] + projb[0]);
    }
    grid.sync();

    // ================= P3: pred strips (64 blocks, 4 b's each) =============
    if (blk < 64){
        int bq = blk >> 2, strip = blk & 3;
        int b0 = bq*4;
        float* entL = smem;          // 4*2304
        float* red2 = smem + 9216;   // [4 q][4 b][128]
        float* hL   = smem + 11264;  // [4 b][128]
        const float* A = ws + ENT_OFF + (size_t)b0*2304;
        for (int i=t; i<9216; i+=512) entL[i] = A[i];
        __syncthreads();
        {
            int c = t & 127, q = t >> 7;
            int col = strip*128 + c;
            const float* W = pW1 + (size_t)(q*576)*512 + col;
            float acc0=0,acc1=0,acc2=0,acc3=0;
            const float* a0 = entL + q*576;
            #pragma unroll 4
            for (int k=0;k<576;++k){
                float w = W[(size_t)k*512];
                acc0 = fmaf(a0[k],        w, acc0);
                acc1 = fmaf(a0[2304+k],   w, acc1);
                acc2 = fmaf(a0[4608+k],   w, acc2);
                acc3 = fmaf(a0[6912+k],   w, acc3);
            }
            float* rp = red2 + (size_t)q*512 + c;
            rp[0]=acc0; rp[128]=acc1; rp[256]=acc2; rp[384]=acc3;
        }
        __syncthreads();
        {
            int bb = t >> 7, c = t & 127;
            int col = strip*128 + c;
            float h = red2[bb*128+c] + red2[512+bb*128+c] + red2[1024+bb*128+c] + red2[1536+bb*128+c];
            hL[bb*128+c] = fmaxf(h + pb1[col], 0.f);
        }
        __syncthreads();
        if (t < 20){
            int bb = t/5, j = t%5;
            float s = 0.f;
            for (int cc=0; cc<128; ++cc)
                s += hL[bb*128+cc] * pW2[(strip*128+cc)*5 + j];
            ws[PRED_OFF + (size_t)((b0+bb)*4 + strip)*5 + j] = s;
        }
    }
    grid.sync();

    // ================= loop: 5 iterations of vr + gate =====================
    for (int it=0; it<5; ++it){
        const float* eS = ws + ((it&1)==0 ? EA_OFF : EB_OFF);
        float*       eD = ws + ((it&1)==0 ? EB_OFF : EA_OFF);

        // ---- vr phase: 256 blocks as (ct=blk>>5 in 0..7, bg=blk&31) ----
        {
            float* eL   = smem;          // 4608
            float* redv = smem + 4608;   // 16*16*17
            int ct = blk >> 5, bg = blk & 31;
            int b0 = bg*2;
            const float* eBase = eS + (size_t)b0*2304;
            for (int idx=t; idx<4608; idx+=512) eL[idx] = eBase[idx];
            if (it==0 && blk < 64 && t >= 256 && t < 261){
                int j = t-256;
                float s = pb2[j];
                for (int q=0;q<4;++q) s += ws[PRED_OFF + (size_t)(blk*4+q)*5 + j];
                out[blk*5+j] = s;
            }
            __syncthreads();
            if (t < 256){
                int tp = t & 15;
                int kq = t >> 4;
                int c0 = ct*64;
                int col = c0 + 4*tp;
                const float* Wp = VrW1 + (size_t)(kq*96)*512 + col;
                int off1 = (kq<8) ? (768 + kq*96) : (1536 + (kq-8)*96);
                int off2 = (kq<8) ? (      kq*96) : (768  + (kq-8)*96);
                const float* pP0 = eL + off1;
                const float* pQ0 = eL + off2;
                const float* pP1 = eL + 2304 + off1;
                const float* pQ1 = eL + 2304 + off2;
                float aP0[4]={0,0,0,0}, aQ0[4]={0,0,0,0}, aP1[4]={0,0,0,0}, aQ1[4]={0,0,0,0};
                #pragma unroll 8
                for (int i=0;i<96;++i){
                    float4 w = *(const float4*)(Wp + (size_t)i*512);
                    float p0 = pP0[i], q0 = pQ0[i], p1 = pP1[i], q1 = pQ1[i];
                    aP0[0]=fmaf(p0,w.x,aP0[0]); aP0[1]=fmaf(p0,w.y,aP0[1]); aP0[2]=fmaf(p0,w.z,aP0[2]); aP0[3]=fmaf(p0,w.w,aP0[3]);
                    aQ0[0]=fmaf(q0,w.x,aQ0[0]); aQ0[1]=fmaf(q0,w.y,aQ0[1]); aQ0[2]=fmaf(q0,w.z,aQ0[2]); aQ0[3]=fmaf(q0,w.w,aQ0[3]);
                    aP1[0]=fmaf(p1,w.x,aP1[0]); aP1[1]=fmaf(p1,w.y,aP1[1]); aP1[2]=fmaf(p1,w.z,aP1[2]); aP1[3]=fmaf(p1,w.w,aP1[3]);
                    aQ1[0]=fmaf(q1,w.x,aQ1[0]); aQ1[1]=fmaf(q1,w.y,aQ1[1]); aQ1[2]=fmaf(q1,w.z,aQ1[2]); aQ1[3]=fmaf(q1,w.w,aQ1[3]);
                }
                float* rp = redv + (kq*16 + tp)*17;
                #pragma unroll
                for (int c=0;c<4;++c){ rp[c]=aP0[c]; rp[4+c]=aQ0[c]; rp[8+c]=aP1[c]; rp[12+c]=aQ1[c]; }
            }
            __syncthreads();
            if (t < 128){
                int bb = t >> 6;
                int tc = t & 63;
                int tp2 = tc >> 2, c = tc & 3;
                int base = bb*8;
                int c0 = ct*64;
                float SP1=0,SP2=0,SQ1=0,SQ2=0;
                #pragma unroll
                for (int k=0;k<8;++k){
                    SP1 += redv[(k*16+tp2)*17 + base + c];
                    SQ1 += redv[(k*16+tp2)*17 + base + 4 + c];
                    SP2 += redv[((k+8)*16+tp2)*17 + base + c];
                    SQ2 += redv[((k+8)*16+tp2)*17 + base + 4 + c];
                }
                int cc = c0 + tc;
                float bv = Vrb1[cc];
                float h0 = fmaxf(SP1+SP2+bv, 0.f);
                float h1 = fmaxf(SQ1+SP2+bv, 0.f);
                float h2 = fmaxf(SQ1+SQ2+bv, 0.f);
                float w20 = VrW2[cc*5+0], w21 = VrW2[cc*5+1], w22 = VrW2[cc*5+2], w23 = VrW2[cc*5+3], w24 = VrW2[cc*5+4];
                float pr[15] = { h0*w20,h0*w21,h0*w22,h0*w23,h0*w24,
                                 h1*w20,h1*w21,h1*w22,h1*w23,h1*w24,
                                 h2*w20,h2*w21,h2*w22,h2*w23,h2*w24 };
                #pragma unroll
                for (int j=0;j<15;++j){
                    float v = pr[j];
                    v += __shfl_down(v, 32);
                    v += __shfl_down(v, 16);
                    v += __shfl_down(v, 8);
                    v += __shfl_down(v, 4);
                    v += __shfl_down(v, 2);
                    v += __shfl_down(v, 1);
                    pr[j] = v;
                }
                if (tc == 0){
                    float* sp = ws + SP_OFF + ((size_t)ct*192 + (size_t)(b0+bb)*3)*5;
                    #pragma unroll
                    for (int j=0;j<15;++j) sp[j] = pr[j];
                }
            }
        }
        grid.sync();

        // ---- gate phase: 192 blocks as (ct=blk/32 in 0..5, bg=blk%32), 128 cols ----
        if (blk < 192){
            float* eL   = smem;           // 4608
            float* uL   = smem + 4608;    // 4608
            float* redg = smem + 9216;    // 16*32*25 = 12800
            float* sL   = smem + 22016;   // 32
            int ct = blk / 32, bg = blk % 32;
            int b0 = bg*2;
            const float* eBase = eS + (size_t)b0*2304;
            for (int idx=t; idx<4608; idx+=512) eL[idx] = eBase[idx];
            if (t < 30){
                int bb = t/15, pc = t%15, cc = pc%5;
                int row = (b0+bb)*3 + pc/5;
                float pre = Vrb2[cc];
                #pragma unroll
                for (int q=0;q<8;++q) pre += ws[SP_OFF + ((size_t)q*192 + row)*5 + cc];
                sL[t] = sigmoidf_(pre);
            }
            __syncthreads();
            for (int idx=t; idx<4608; idx+=512){
                int r = idx / 768;
                int k = idx - r*768;
                int bb = r / 3;  int p = r - bb*3;
                const float* s = sL + bb*15 + p*5;
                float a = Arb[k] + s[0]*ArW[k] + s[1]*ArW[768+k] + s[2]*ArW[1536+k]
                                 + s[3]*ArW[2304+k] + s[4]*ArW[3072+k];
                uL[idx] = a * eL[idx];
            }
            __syncthreads();
            {
                int tp = t & 31, kq = t >> 5;
                int c0 = ct*128;
                int col = c0 + 4*tp;
                const float* Wp = gW + (size_t)(kq*96)*768 + col;
                const float* A = (kq<8) ? uL : eL;
                int kb = (kq & 7)*96;
                float acc[6][4];
                #pragma unroll
                for (int r=0;r<6;++r){ acc[r][0]=0.f; acc[r][1]=0.f; acc[r][2]=0.f; acc[r][3]=0.f; }
                #pragma unroll 4
                for (int i=0;i<96;++i){
                    float4 w = *(const float4*)(Wp + (size_t)i*768);
                    #pragma unroll
                    for (int r=0;r<6;++r){
                        float a = A[r*768 + kb + i];
                        acc[r][0] = fmaf(a, w.x, acc[r][0]);
                        acc[r][1] = fmaf(a, w.y, acc[r][1]);
                        acc[r][2] = fmaf(a, w.z, acc[r][2]);
                        acc[r][3] = fmaf(a, w.w, acc[r][3]);
                    }
                }
                float* rp = redg + (kq*32+tp)*25;
                #pragma unroll
                for (int r=0;r<6;++r){
                    rp[r*4+0]=acc[r][0]; rp[r*4+1]=acc[r][1]; rp[r*4+2]=acc[r][2]; rp[r*4+3]=acc[r][3];
                }
            }
            __syncthreads();
            for (int o=t; o<768; o+=512){
                int tc = o & 127, rr = o >> 7;
                int tp2 = tc >> 2, c = tc & 3;
                int bb = rr/3, p = rr - bb*3;
                float gp = 0.f;
                #pragma unroll
                for (int k=0;k<16;++k) gp += redg[(k*32+tp2)*25 + rr*4 + c];
                int jc = ct*128 + tc;
                float g = sigmoidf_(gp + gb[jc]);
                float e = eL[bb*2304 + p*768 + jc];
                float u = uL[bb*2304 + p*768 + jc];
                float val = g*e + (1.f-g)*u;
                size_t oi = ((size_t)(b0+bb)*3 + p)*768 + jc;
                eD[oi] = val;
                if (it==4) out[512 + oi] = val;
            }
        }
        grid.sync();
    }
}

extern "C" void kernel_launch(void* const* d_in, const int* in_sizes, int n_in,
                              void* d_out, int out_size, void* d_ws, size_t ws_size,
                              hipStream_t stream)
{
    const float* enc     = (const float*)d_in[0];
    const int*   ent_pos = (const int*)d_in[1];
    const float* ArW     = (const float*)d_in[2];
    const float* Arb     = (const float*)d_in[3];
    const float* VrW1    = (const float*)d_in[4];
    const float* Vrb1    = (const float*)d_in[5];
    const float* VrW2    = (const float*)d_in[6];
    const float* Vrb2    = (const float*)d_in[7];
    const float* gateW   = (const float*)d_in[8];
    const float* gateb   = (const float*)d_in[9];
    const float* predW1  = (const float*)d_in[10];
    const float* predb1  = (const float*)d_in[11];
    const float* predW2  = (const float*)d_in[12];
    const float* predb2  = (const float*)d_in[13];
    const float* projW   = (const float*)d_in[14];
    const float* projb   = (const float*)d_in[15];
    float* out = (float*)d_out;
    float* ws  = (float*)d_ws;

    void* args[] = {
        (void*)&enc, (void*)&ent_pos,
        (void*)&ArW, (void*)&Arb,
        (void*)&VrW1, (void*)&Vrb1, (void*)&VrW2, (void*)&Vrb2,
        (void*)&gateW, (void*)&gateb,
        (void*)&predW1, (void*)&predb1, (void*)&predW2, (void*)&predb2,
        (void*)&projW, (void*)&projb,
        (void*)&out, (void*)&ws
    };
    hipLaunchCooperativeKernel((const void*)k_mega, dim3(256), dim3(512), args, 0, stream);
}

// Round 8
// 183.827 us; speedup vs baseline: 3.1326x; 3.1326x over previous
//
#include <hip/hip_runtime.h>
#include <hip/hip_bf16.h>
#include <math.h>

#define NEGF (-1e30f)

// ws float offsets
#define ENT_OFF  1179648u    // ent (B,3,D) = 147456
#define EA_OFF   1327104u    // e state A
#define EB_OFF   1474560u    // e state B
#define SP_OFF   1622016u    // s-partials [8][192][5] = 7680
#define PP_OFF   1637376u    // pred partials 8*64*512 = 262144

__device__ __forceinline__ float sigmoidf_(float x){ return 1.0f/(1.0f+expf(-x)); }

// ---- span max, merged: one block per (b,ent); full span + ent/eA + proj ----
__global__ __launch_bounds__(192) void k_span(
    const float* __restrict__ enc, const int* __restrict__ ent_pos,
    const float* __restrict__ projW, const float* __restrict__ projb,
    float* __restrict__ ws, float* __restrict__ out)
{
    __shared__ float red[4];
    int bi = blockIdx.x; int t = threadIdx.x;
    int b = bi/3;
    int st = ent_pos[bi*2+0], en = ent_pos[bi*2+1];
    float4 m = make_float4(NEGF,NEGF,NEGF,NEGF);
    const float4* e4 = (const float4*)enc + (size_t)b*512*192 + t;
    int r = st;
    for (; r+3<=en; r+=4){
        float4 v0 = e4[(size_t)(r  )*192];
        float4 v1 = e4[(size_t)(r+1)*192];
        float4 v2 = e4[(size_t)(r+2)*192];
        float4 v3 = e4[(size_t)(r+3)*192];
        m.x=fmaxf(m.x,fmaxf(fmaxf(v0.x,v1.x),fmaxf(v2.x,v3.x)));
        m.y=fmaxf(m.y,fmaxf(fmaxf(v0.y,v1.y),fmaxf(v2.y,v3.y)));
        m.z=fmaxf(m.z,fmaxf(fmaxf(v0.z,v1.z),fmaxf(v2.z,v3.z)));
        m.w=fmaxf(m.w,fmaxf(fmaxf(v0.w,v1.w),fmaxf(v2.w,v3.w)));
    }
    for (; r<=en; ++r){
        float4 v = e4[(size_t)r*192];
        m.x=fmaxf(m.x,v.x); m.y=fmaxf(m.y,v.y); m.z=fmaxf(m.z,v.z); m.w=fmaxf(m.w,v.w);
    }
    ((float4*)(ws+ENT_OFF))[bi*192+t] = m;
    ((float4*)(ws+EA_OFF))[bi*192+t] = m;
    float4 w = ((const float4*)projW)[t];
    float v = m.x*w.x + m.y*w.y + m.z*w.z + m.w*w.w;
    v += __shfl_down(v, 32);
    v += __shfl_down(v, 16);
    v += __shfl_down(v, 8);
    v += __shfl_down(v, 4);
    v += __shfl_down(v, 2);
    v += __shfl_down(v, 1);
    if ((t & 63) == 0) red[t>>6] = v;
    __syncthreads();
    if (t==0) out[320 + bi] = sigmoidf_(red[0]+red[1]+red[2] + projb[0]);
}

// ---- pred head: split-K partials (64 x 512, K=2304 in 8 chunks) ----
__global__ __launch_bounds__(256) void k_pred_part(
    const float* __restrict__ predW1, float* __restrict__ ws)
{
    int ct = blockIdx.x, rb = blockIdx.y, ks = blockIdx.z;
    int tx = threadIdx.x & 31, ty = threadIdx.x >> 5;
    int row = rb*8+ty, col = ct*32+tx;
    const float* A = ws + ENT_OFF + (size_t)row*2304 + ks*288;
    const float* W = predW1 + (size_t)(ks*288)*512 + col;
    float acc = 0.f;
    #pragma unroll 4
    for (int k=0;k<288;++k){ acc = fmaf(A[k], W[(size_t)k*512], acc); }
    ws[PP_OFF + ((size_t)(ks*64+row))*512 + col] = acc;
}

// ---- vr fused: 1D grid; g<256: GEMM blocks (ct=g&7 -> XCD-pinned slice);
//      g>=256 (only when it==0): pred finish blocks ----
__global__ __launch_bounds__(256) void k_vr_fused(
    const float* __restrict__ W1, const float* __restrict__ b1,
    const float* __restrict__ W2, const float* __restrict__ eSrc,
    const float* __restrict__ pb1, const float* __restrict__ pW2,
    const float* __restrict__ pb2,
    float* __restrict__ ws, float* __restrict__ out)
{
    __shared__ float eL[4608];      // [2 b][3 p][768]
    __shared__ float red[16*16*17]; // [kq16][tp16][16+pad]
    int g = blockIdx.x;
    int t = threadIdx.x;
    if (g >= 256){
        // pred finish: 8 blocks, each 8 batches; 32 lanes per batch
        int bx = g - 256;
        int gid = t >> 5, l = t & 31;
        int b = bx*8 + gid;
        float acc0=0,acc1=0,acc2=0,acc3=0,acc4=0;
        for (int c = l; c < 512; c += 32){
            float h = 0.f;
            #pragma unroll
            for (int ks=0;ks<8;++ks) h += ws[PP_OFF + ((size_t)(ks*64+b))*512 + c];
            h = fmaxf(h + pb1[c], 0.f);
            acc0 = fmaf(h, pW2[c*5+0], acc0);
            acc1 = fmaf(h, pW2[c*5+1], acc1);
            acc2 = fmaf(h, pW2[c*5+2], acc2);
            acc3 = fmaf(h, pW2[c*5+3], acc3);
            acc4 = fmaf(h, pW2[c*5+4], acc4);
        }
        #pragma unroll
        for (int s=16; s>0; s>>=1){
            acc0 += __shfl_down(acc0, s, 32);
            acc1 += __shfl_down(acc1, s, 32);
            acc2 += __shfl_down(acc2, s, 32);
            acc3 += __shfl_down(acc3, s, 32);
            acc4 += __shfl_down(acc4, s, 32);
        }
        if (l == 0){
            out[b*5+0] = acc0 + pb2[0];
            out[b*5+1] = acc1 + pb2[1];
            out[b*5+2] = acc2 + pb2[2];
            out[b*5+3] = acc3 + pb2[3];
            out[b*5+4] = acc4 + pb2[4];
        }
        return;
    }
    int ct = g & 7, bg = g >> 3;
    int b0 = bg*2;
    const float* eBase = eSrc + (size_t)b0*2304;
    for (int idx=t; idx<4608; idx+=256) eL[idx] = eBase[idx];
    __syncthreads();

    int tp = t & 15;
    int kq = t >> 4;             // 0..15, K-chunk of 96
    int c0 = ct*64;
    int col = c0 + 4*tp;
    const float* Wp = W1 + (size_t)(kq*96)*512 + col;
    int off1 = (kq<8) ? (768 + kq*96) : (1536 + (kq-8)*96);
    int off2 = (kq<8) ? (      kq*96) : (768  + (kq-8)*96);
    const float* pP0 = eL + off1;
    const float* pQ0 = eL + off2;
    const float* pP1 = eL + 2304 + off1;
    const float* pQ1 = eL + 2304 + off2;
    float aP0[4]={0,0,0,0}, aQ0[4]={0,0,0,0}, aP1[4]={0,0,0,0}, aQ1[4]={0,0,0,0};
    #pragma unroll 8
    for (int i=0;i<96;++i){
        float4 w = *(const float4*)(Wp + (size_t)i*512);
        float p0 = pP0[i], q0 = pQ0[i], p1 = pP1[i], q1 = pQ1[i];
        aP0[0]=fmaf(p0,w.x,aP0[0]); aP0[1]=fmaf(p0,w.y,aP0[1]); aP0[2]=fmaf(p0,w.z,aP0[2]); aP0[3]=fmaf(p0,w.w,aP0[3]);
        aQ0[0]=fmaf(q0,w.x,aQ0[0]); aQ0[1]=fmaf(q0,w.y,aQ0[1]); aQ0[2]=fmaf(q0,w.z,aQ0[2]); aQ0[3]=fmaf(q0,w.w,aQ0[3]);
        aP1[0]=fmaf(p1,w.x,aP1[0]); aP1[1]=fmaf(p1,w.y,aP1[1]); aP1[2]=fmaf(p1,w.z,aP1[2]); aP1[3]=fmaf(p1,w.w,aP1[3]);
        aQ1[0]=fmaf(q1,w.x,aQ1[0]); aQ1[1]=fmaf(q1,w.y,aQ1[1]); aQ1[2]=fmaf(q1,w.z,aQ1[2]); aQ1[3]=fmaf(q1,w.w,aQ1[3]);
    }
    float* rp = red + (kq*16 + tp)*17;
    #pragma unroll
    for (int c=0;c<4;++c){ rp[c]=aP0[c]; rp[4+c]=aQ0[c]; rp[8+c]=aP1[c]; rp[12+c]=aQ1[c]; }
    __syncthreads();

    if (t < 128){
        int bb = t >> 6;
        int tc = t & 63;
        int tp2 = tc >> 2, c = tc & 3;
        int base = bb*8;
        float SP1=0,SP2=0,SQ1=0,SQ2=0;
        #pragma unroll
        for (int k=0;k<8;++k){
            SP1 += red[(k*16+tp2)*17 + base + c];
            SQ1 += red[(k*16+tp2)*17 + base + 4 + c];
            SP2 += red[((k+8)*16+tp2)*17 + base + c];
            SQ2 += red[((k+8)*16+tp2)*17 + base + 4 + c];
        }
        int cc = c0 + tc;
        float bv = b1[cc];
        float h0 = fmaxf(SP1+SP2+bv, 0.f);
        float h1 = fmaxf(SQ1+SP2+bv, 0.f);
        float h2 = fmaxf(SQ1+SQ2+bv, 0.f);
        float w20 = W2[cc*5+0], w21 = W2[cc*5+1], w22 = W2[cc*5+2], w23 = W2[cc*5+3], w24 = W2[cc*5+4];
        float pr[15] = { h0*w20,h0*w21,h0*w22,h0*w23,h0*w24,
                         h1*w20,h1*w21,h1*w22,h1*w23,h1*w24,
                         h2*w20,h2*w21,h2*w22,h2*w23,h2*w24 };
        #pragma unroll
        for (int j=0;j<15;++j){
            float v = pr[j];
            v += __shfl_down(v, 32);
            v += __shfl_down(v, 16);
            v += __shfl_down(v, 8);
            v += __shfl_down(v, 4);
            v += __shfl_down(v, 2);
            v += __shfl_down(v, 1);
            pr[j] = v;
        }
        if (tc == 0){
            float* sp = ws + SP_OFF + ((size_t)ct*192 + (size_t)(b0+bb)*3)*5;
            #pragma unroll
            for (int j=0;j<15;++j) sp[j] = pr[j];
        }
    }
}

// ---- gate fused: 1D grid 256, 384 thr; ct=g&7 -> 96-col slice XCD-pinned ----
__global__ __launch_bounds__(384) void k_gate_fused(
    const float* __restrict__ gW, const float* __restrict__ gb,
    const float* __restrict__ ArW, const float* __restrict__ Arb,
    const float* __restrict__ Vb2,
    const float* __restrict__ eSrc, float* __restrict__ eDst,
    float* __restrict__ ws, float* __restrict__ finalOut)
{
    __shared__ float eL[4608];
    __shared__ float uL[4608];
    __shared__ float red[16*24*25];  // [kq16][tp24][24+pad]
    __shared__ float sL[32];
    int g = blockIdx.x;
    int t = threadIdx.x;
    int ct = g & 7, bg = g >> 3;
    int b0 = bg*2;
    const float* eBase = eSrc + (size_t)b0*2304;
    for (int idx=t; idx<4608; idx+=384) eL[idx] = eBase[idx];
    if (t < 30){
        int bb = t/15, pc = t%15, cc = pc%5;
        int row = (b0+bb)*3 + pc/5;
        float pre = Vb2[cc];
        #pragma unroll
        for (int q=0;q<8;++q) pre += ws[SP_OFF + ((size_t)q*192 + row)*5 + cc];
        sL[t] = sigmoidf_(pre);
    }
    __syncthreads();
    for (int idx=t; idx<4608; idx+=384){
        int r = idx / 768;
        int k = idx - r*768;
        int bb = r / 3;  int p = r - bb*3;
        const float* s = sL + bb*15 + p*5;
        float a = Arb[k] + s[0]*ArW[k] + s[1]*ArW[768+k] + s[2]*ArW[1536+k]
                         + s[3]*ArW[2304+k] + s[4]*ArW[3072+k];
        uL[idx] = a * eL[idx];
    }
    __syncthreads();

    int kq = t / 24, tp = t - kq*24;   // kq 0..15, tp 0..23
    int c0 = ct*96;
    int col = c0 + 4*tp;
    const float* Wp = gW + (size_t)(kq*96)*768 + col;
    const float* A = (kq<8) ? uL : eL;
    int kb = (kq & 7)*96;
    float acc[6][4];
    #pragma unroll
    for (int r=0;r<6;++r){ acc[r][0]=0.f; acc[r][1]=0.f; acc[r][2]=0.f; acc[r][3]=0.f; }
    #pragma unroll 4
    for (int i=0;i<96;++i){
        float4 w = *(const float4*)(Wp + (size_t)i*768);
        #pragma unroll
        for (int r=0;r<6;++r){
            float a = A[r*768 + kb + i];
            acc[r][0] = fmaf(a, w.x, acc[r][0]);
            acc[r][1] = fmaf(a, w.y, acc[r][1]);
            acc[r][2] = fmaf(a, w.z, acc[r][2]);
            acc[r][3] = fmaf(a, w.w, acc[r][3]);
        }
    }
    float* rp = red + (kq*24+tp)*25;
    #pragma unroll
    for (int r=0;r<6;++r){
        rp[r*4+0]=acc[r][0]; rp[r*4+1]=acc[r][1]; rp[r*4+2]=acc[r][2]; rp[r*4+3]=acc[r][3];
    }
    __syncthreads();

    for (int o=t; o<576; o+=384){
        int rr = o / 96, tc = o - rr*96;   // row 0..5, col within 96
        int tp2 = tc >> 2, c = tc & 3;
        int bb = rr/3, p = rr - bb*3;
        float gp = 0.f;
        #pragma unroll
        for (int k=0;k<16;++k) gp += red[(k*24+tp2)*25 + rr*4 + c];
        int jc = c0 + tc;
        float gv = sigmoidf_(gp + gb[jc]);
        float e = eL[bb*2304 + p*768 + jc];
        float u = uL[bb*2304 + p*768 + jc];
        float val = gv*e + (1.f-gv)*u;
        size_t oi = ((size_t)(b0+bb)*3 + p)*768 + jc;
        eDst[oi] = val;
        if (finalOut) finalOut[oi] = val;
    }
}

extern "C" void kernel_launch(void* const* d_in, const int* in_sizes, int n_in,
                              void* d_out, int out_size, void* d_ws, size_t ws_size,
                              hipStream_t stream)
{
    const float* enc     = (const float*)d_in[0];
    const int*   ent_pos = (const int*)d_in[1];
    const float* ArW     = (const float*)d_in[2];
    const float* Arb     = (const float*)d_in[3];
    const float* VrW1    = (const float*)d_in[4];
    const float* Vrb1    = (const float*)d_in[5];
    const float* VrW2    = (const float*)d_in[6];
    const float* Vrb2    = (const float*)d_in[7];
    const float* gateW   = (const float*)d_in[8];
    const float* gateb   = (const float*)d_in[9];
    const float* predW1  = (const float*)d_in[10];
    const float* predb1  = (const float*)d_in[11];
    const float* predW2  = (const float*)d_in[12];
    const float* predb2  = (const float*)d_in[13];
    const float* projW   = (const float*)d_in[14];
    const float* projb   = (const float*)d_in[15];
    float* out = (float*)d_out;
    float* ws  = (float*)d_ws;

    hipLaunchKernelGGL(k_span, dim3(192), dim3(192), 0, stream, enc, ent_pos, projW, projb, ws, out);
    hipLaunchKernelGGL(k_pred_part, dim3(16,8,8), dim3(256), 0, stream, predW1, ws);
    for (int it=0; it<5; ++it){
        float* eS = ws + ((it&1)==0 ? EA_OFF : EB_OFF);
        float* eD = ws + ((it&1)==0 ? EB_OFF : EA_OFF);
        hipLaunchKernelGGL(k_vr_fused, dim3(it==0 ? 264 : 256), dim3(256), 0, stream,
                           VrW1, Vrb1, VrW2, eS, predb1, predW2, predb2, ws, out);
        hipLaunchKernelGGL(k_gate_fused, dim3(256), dim3(384), 0, stream, gateW, gateb, ArW, Arb, Vrb2,
                           eS, eD, ws, (it==4) ? (out+512) : (float*)nullptr);
    }
}

// Round 9
// 159.495 us; speedup vs baseline: 3.6105x; 1.1526x over previous
//
#include <hip/hip_runtime.h>
#include <hip/hip_bf16.h>
#include <math.h>

#define NEGF (-1e30f)

// ws float offsets
#define P_OFF    0u          // span partials [192][16][768] = 2359296 (dead after reduce)
#define PP_OFF   0u          // pred partials 8*64*512 = 262144 (aliases dead P region)
#define ENT_OFF  2359296u    // ent (B,3,D) = 147456
#define EA_OFF   2506752u    // e state A
#define EB_OFF   2654208u    // e state B
#define SP_OFF   2801664u    // s-partials [8][192][5] = 7680
// total 2809344 floats = 11.2 MB

__device__ __forceinline__ float sigmoidf_(float x){ return 1.0f/(1.0f+expf(-x)); }

// ---- span max partials: 32-row chunks, early-exit on empty intersection ----
__global__ __launch_bounds__(192) void k_span_partial(
    const float* __restrict__ enc, const int* __restrict__ ent_pos, float* __restrict__ ws)
{
    int c = blockIdx.x, bi = blockIdx.y, t = threadIdx.x;
    int b = bi/3;
    int st = ent_pos[bi*2+0], en = ent_pos[bi*2+1];
    int r0 = max(st, c*32), r1 = min(en, c*32+31);
    if (r0 > r1) return;
    float4 m = make_float4(NEGF,NEGF,NEGF,NEGF);
    const float4* e4 = (const float4*)enc + (size_t)b*512*192 + t;
    int r = r0;
    for (; r+3<=r1; r+=4){
        float4 v0 = e4[(size_t)(r  )*192];
        float4 v1 = e4[(size_t)(r+1)*192];
        float4 v2 = e4[(size_t)(r+2)*192];
        float4 v3 = e4[(size_t)(r+3)*192];
        m.x=fmaxf(m.x,fmaxf(fmaxf(v0.x,v1.x),fmaxf(v2.x,v3.x)));
        m.y=fmaxf(m.y,fmaxf(fmaxf(v0.y,v1.y),fmaxf(v2.y,v3.y)));
        m.z=fmaxf(m.z,fmaxf(fmaxf(v0.z,v1.z),fmaxf(v2.z,v3.z)));
        m.w=fmaxf(m.w,fmaxf(fmaxf(v0.w,v1.w),fmaxf(v2.w,v3.w)));
    }
    for (; r<=r1; ++r){
        float4 v = e4[(size_t)r*192];
        m.x=fmaxf(m.x,v.x); m.y=fmaxf(m.y,v.y); m.z=fmaxf(m.z,v.z); m.w=fmaxf(m.w,v.w);
    }
    ((float4*)(ws+P_OFF))[((size_t)bi*16 + c)*192 + t] = m;
}

// ---- span reduce: intersection-aware; -> ent, eA, ent_score ----
__global__ __launch_bounds__(192) void k_span_reduce(
    const int* __restrict__ ent_pos,
    const float* __restrict__ projW, const float* __restrict__ projb,
    float* __restrict__ ws, float* __restrict__ out)
{
    __shared__ float red[4];
    int bi = blockIdx.x; int t = threadIdx.x;
    int st = ent_pos[bi*2+0], en = ent_pos[bi*2+1];
    float4 m = make_float4(NEGF,NEGF,NEGF,NEGF);
    const float4* p4 = (const float4*)(ws+P_OFF);
    for (int c=0;c<16;++c){
        if (c*32 <= en && c*32+31 >= st){
            float4 v = p4[((size_t)bi*16 + c)*192 + t];
            m.x=fmaxf(m.x,v.x); m.y=fmaxf(m.y,v.y); m.z=fmaxf(m.z,v.z); m.w=fmaxf(m.w,v.w);
        }
    }
    ((float4*)(ws+ENT_OFF))[bi*192+t] = m;
    ((float4*)(ws+EA_OFF))[bi*192+t] = m;
    float4 w = ((const float4*)projW)[t];
    float v = m.x*w.x + m.y*w.y + m.z*w.z + m.w*w.w;
    v += __shfl_down(v, 32);
    v += __shfl_down(v, 16);
    v += __shfl_down(v, 8);
    v += __shfl_down(v, 4);
    v += __shfl_down(v, 2);
    v += __shfl_down(v, 1);
    if ((t & 63) == 0) red[t>>6] = v;
    __syncthreads();
    if (t==0) out[320 + bi] = sigmoidf_(red[0]+red[1]+red[2] + projb[0]);
}

// ---- pred head: split-K partials (64 x 512, K=2304 in 8 chunks) ----
__global__ __launch_bounds__(256) void k_pred_part(
    const float* __restrict__ predW1, float* __restrict__ ws)
{
    int ct = blockIdx.x, rb = blockIdx.y, ks = blockIdx.z;
    int tx = threadIdx.x & 31, ty = threadIdx.x >> 5;
    int row = rb*8+ty, col = ct*32+tx;
    const float* A = ws + ENT_OFF + (size_t)row*2304 + ks*288;
    const float* W = predW1 + (size_t)(ks*288)*512 + col;
    float acc = 0.f;
    #pragma unroll 4
    for (int k=0;k<288;++k){ acc = fmaf(A[k], W[(size_t)k*512], acc); }
    ws[PP_OFF + ((size_t)(ks*64+row))*512 + col] = acc;
}

// ---- vr fused: 1D grid; g<256: GEMM blocks (ct=g&7 -> XCD-pinned slice);
//      g>=256 (only when it==0): pred finish blocks ----
__global__ __launch_bounds__(256) void k_vr_fused(
    const float* __restrict__ W1, const float* __restrict__ b1,
    const float* __restrict__ W2, const float* __restrict__ eSrc,
    const float* __restrict__ pb1, const float* __restrict__ pW2,
    const float* __restrict__ pb2,
    float* __restrict__ ws, float* __restrict__ out)
{
    __shared__ float eL[4608];      // [2 b][3 p][768]
    __shared__ float red[16*16*17]; // [kq16][tp16][16+pad]
    int g = blockIdx.x;
    int t = threadIdx.x;
    if (g >= 256){
        // pred finish: 8 blocks, each 8 batches; 32 lanes per batch
        int bx = g - 256;
        int gid = t >> 5, l = t & 31;
        int b = bx*8 + gid;
        float acc0=0,acc1=0,acc2=0,acc3=0,acc4=0;
        for (int c = l; c < 512; c += 32){
            float h = 0.f;
            #pragma unroll
            for (int ks=0;ks<8;++ks) h += ws[PP_OFF + ((size_t)(ks*64+b))*512 + c];
            h = fmaxf(h + pb1[c], 0.f);
            acc0 = fmaf(h, pW2[c*5+0], acc0);
            acc1 = fmaf(h, pW2[c*5+1], acc1);
            acc2 = fmaf(h, pW2[c*5+2], acc2);
            acc3 = fmaf(h, pW2[c*5+3], acc3);
            acc4 = fmaf(h, pW2[c*5+4], acc4);
        }
        #pragma unroll
        for (int s=16; s>0; s>>=1){
            acc0 += __shfl_down(acc0, s, 32);
            acc1 += __shfl_down(acc1, s, 32);
            acc2 += __shfl_down(acc2, s, 32);
            acc3 += __shfl_down(acc3, s, 32);
            acc4 += __shfl_down(acc4, s, 32);
        }
        if (l == 0){
            out[b*5+0] = acc0 + pb2[0];
            out[b*5+1] = acc1 + pb2[1];
            out[b*5+2] = acc2 + pb2[2];
            out[b*5+3] = acc3 + pb2[3];
            out[b*5+4] = acc4 + pb2[4];
        }
        return;
    }
    int ct = g & 7, bg = g >> 3;
    int b0 = bg*2;
    const float* eBase = eSrc + (size_t)b0*2304;
    for (int idx=t; idx<4608; idx+=256) eL[idx] = eBase[idx];
    __syncthreads();

    int tp = t & 15;
    int kq = t >> 4;             // 0..15, K-chunk of 96
    int c0 = ct*64;
    int col = c0 + 4*tp;
    const float* Wp = W1 + (size_t)(kq*96)*512 + col;
    int off1 = (kq<8) ? (768 + kq*96) : (1536 + (kq-8)*96);
    int off2 = (kq<8) ? (      kq*96) : (768  + (kq-8)*96);
    const float* pP0 = eL + off1;
    const float* pQ0 = eL + off2;
    const float* pP1 = eL + 2304 + off1;
    const float* pQ1 = eL + 2304 + off2;
    float aP0[4]={0,0,0,0}, aQ0[4]={0,0,0,0}, aP1[4]={0,0,0,0}, aQ1[4]={0,0,0,0};
    #pragma unroll 8
    for (int i=0;i<96;++i){
        float4 w = *(const float4*)(Wp + (size_t)i*512);
        float p0 = pP0[i], q0 = pQ0[i], p1 = pP1[i], q1 = pQ1[i];
        aP0[0]=fmaf(p0,w.x,aP0[0]); aP0[1]=fmaf(p0,w.y,aP0[1]); aP0[2]=fmaf(p0,w.z,aP0[2]); aP0[3]=fmaf(p0,w.w,aP0[3]);
        aQ0[0]=fmaf(q0,w.x,aQ0[0]); aQ0[1]=fmaf(q0,w.y,aQ0[1]); aQ0[2]=fmaf(q0,w.z,aQ0[2]); aQ0[3]=fmaf(q0,w.w,aQ0[3]);
        aP1[0]=fmaf(p1,w.x,aP1[0]); aP1[1]=fmaf(p1,w.y,aP1[1]); aP1[2]=fmaf(p1,w.z,aP1[2]); aP1[3]=fmaf(p1,w.w,aP1[3]);
        aQ1[0]=fmaf(q1,w.x,aQ1[0]); aQ1[1]=fmaf(q1,w.y,aQ1[1]); aQ1[2]=fmaf(q1,w.z,aQ1[2]); aQ1[3]=fmaf(q1,w.w,aQ1[3]);
    }
    float* rp = red + (kq*16 + tp)*17;
    #pragma unroll
    for (int c=0;c<4;++c){ rp[c]=aP0[c]; rp[4+c]=aQ0[c]; rp[8+c]=aP1[c]; rp[12+c]=aQ1[c]; }
    __syncthreads();

    if (t < 128){
        int bb = t >> 6;
        int tc = t & 63;
        int tp2 = tc >> 2, c = tc & 3;
        int base = bb*8;
        float SP1=0,SP2=0,SQ1=0,SQ2=0;
        #pragma unroll
        for (int k=0;k<8;++k){
            SP1 += red[(k*16+tp2)*17 + base + c];
            SQ1 += red[(k*16+tp2)*17 + base + 4 + c];
            SP2 += red[((k+8)*16+tp2)*17 + base + c];
            SQ2 += red[((k+8)*16+tp2)*17 + base + 4 + c];
        }
        int cc = c0 + tc;
        float bv = b1[cc];
        float h0 = fmaxf(SP1+SP2+bv, 0.f);
        float h1 = fmaxf(SQ1+SP2+bv, 0.f);
        float h2 = fmaxf(SQ1+SQ2+bv, 0.f);
        float w20 = W2[cc*5+0], w21 = W2[cc*5+1], w22 = W2[cc*5+2], w23 = W2[cc*5+3], w24 = W2[cc*5+4];
        float pr[15] = { h0*w20,h0*w21,h0*w22,h0*w23,h0*w24,
                         h1*w20,h1*w21,h1*w22,h1*w23,h1*w24,
                         h2*w20,h2*w21,h2*w22,h2*w23,h2*w24 };
        #pragma unroll
        for (int j=0;j<15;++j){
            float v = pr[j];
            v += __shfl_down(v, 32);
            v += __shfl_down(v, 16);
            v += __shfl_down(v, 8);
            v += __shfl_down(v, 4);
            v += __shfl_down(v, 2);
            v += __shfl_down(v, 1);
            pr[j] = v;
        }
        if (tc == 0){
            float* sp = ws + SP_OFF + ((size_t)ct*192 + (size_t)(b0+bb)*3)*5;
            #pragma unroll
            for (int j=0;j<15;++j) sp[j] = pr[j];
        }
    }
}

// ---- gate fused: 1D grid 256, 384 thr; ct=g&7 -> 96-col slice XCD-pinned ----
__global__ __launch_bounds__(384) void k_gate_fused(
    const float* __restrict__ gW, const float* __restrict__ gb,
    const float* __restrict__ ArW, const float* __restrict__ Arb,
    const float* __restrict__ Vb2,
    const float* __restrict__ eSrc, float* __restrict__ eDst,
    float* __restrict__ ws, float* __restrict__ finalOut)
{
    __shared__ float eL[4608];
    __shared__ float uL[4608];
    __shared__ float red[16*24*25];  // [kq16][tp24][24+pad]
    __shared__ float sL[32];
    int g = blockIdx.x;
    int t = threadIdx.x;
    int ct = g & 7, bg = g >> 3;
    int b0 = bg*2;
    const float* eBase = eSrc + (size_t)b0*2304;
    for (int idx=t; idx<4608; idx+=384) eL[idx] = eBase[idx];
    if (t < 30){
        int bb = t/15, pc = t%15, cc = pc%5;
        int row = (b0+bb)*3 + pc/5;
        float pre = Vb2[cc];
        #pragma unroll
        for (int q=0;q<8;++q) pre += ws[SP_OFF + ((size_t)q*192 + row)*5 + cc];
        sL[t] = sigmoidf_(pre);
    }
    __syncthreads();
    for (int idx=t; idx<4608; idx+=384){
        int r = idx / 768;
        int k = idx - r*768;
        int bb = r / 3;  int p = r - bb*3;
        const float* s = sL + bb*15 + p*5;
        float a = Arb[k] + s[0]*ArW[k] + s[1]*ArW[768+k] + s[2]*ArW[1536+k]
                         + s[3]*ArW[2304+k] + s[4]*ArW[3072+k];
        uL[idx] = a * eL[idx];
    }
    __syncthreads();

    int kq = t / 24, tp = t - kq*24;   // kq 0..15, tp 0..23
    int c0 = ct*96;
    int col = c0 + 4*tp;
    const float* Wp = gW + (size_t)(kq*96)*768 + col;
    const float* A = (kq<8) ? uL : eL;
    int kb = (kq & 7)*96;
    float acc[6][4];
    #pragma unroll
    for (int r=0;r<6;++r){ acc[r][0]=0.f; acc[r][1]=0.f; acc[r][2]=0.f; acc[r][3]=0.f; }
    #pragma unroll 4
    for (int i=0;i<96;++i){
        float4 w = *(const float4*)(Wp + (size_t)i*768);
        #pragma unroll
        for (int r=0;r<6;++r){
            float a = A[r*768 + kb + i];
            acc[r][0] = fmaf(a, w.x, acc[r][0]);
            acc[r][1] = fmaf(a, w.y, acc[r][1]);
            acc[r][2] = fmaf(a, w.z, acc[r][2]);
            acc[r][3] = fmaf(a, w.w, acc[r][3]);
        }
    }
    float* rp = red + (kq*24+tp)*25;
    #pragma unroll
    for (int r=0;r<6;++r){
        rp[r*4+0]=acc[r][0]; rp[r*4+1]=acc[r][1]; rp[r*4+2]=acc[r][2]; rp[r*4+3]=acc[r][3];
    }
    __syncthreads();

    for (int o=t; o<576; o+=384){
        int rr = o / 96, tc = o - rr*96;   // row 0..5, col within 96
        int tp2 = tc >> 2, c = tc & 3;
        int bb = rr/3, p = rr - bb*3;
        float gp = 0.f;
        #pragma unroll
        for (int k=0;k<16;++k) gp += red[(k*24+tp2)*25 + rr*4 + c];
        int jc = c0 + tc;
        float gv = sigmoidf_(gp + gb[jc]);
        float e = eL[bb*2304 + p*768 + jc];
        float u = uL[bb*2304 + p*768 + jc];
        float val = gv*e + (1.f-gv)*u;
        size_t oi = ((size_t)(b0+bb)*3 + p)*768 + jc;
        eDst[oi] = val;
        if (finalOut) finalOut[oi] = val;
    }
}

extern "C" void kernel_launch(void* const* d_in, const int* in_sizes, int n_in,
                              void* d_out, int out_size, void* d_ws, size_t ws_size,
                              hipStream_t stream)
{
    const float* enc     = (const float*)d_in[0];
    const int*   ent_pos = (const int*)d_in[1];
    const float* ArW     = (const float*)d_in[2];
    const float* Arb     = (const float*)d_in[3];
    const float* VrW1    = (const float*)d_in[4];
    const float* Vrb1    = (const float*)d_in[5];
    const float* VrW2    = (const float*)d_in[6];
    const float* Vrb2    = (const float*)d_in[7];
    const float* gateW   = (const float*)d_in[8];
    const float* gateb   = (const float*)d_in[9];
    const float* predW1  = (const float*)d_in[10];
    const float* predb1  = (const float*)d_in[11];
    const float* predW2  = (const float*)d_in[12];
    const float* predb2  = (const float*)d_in[13];
    const float* projW   = (const float*)d_in[14];
    const float* projb   = (const float*)d_in[15];
    float* out = (float*)d_out;
    float* ws  = (float*)d_ws;

    hipLaunchKernelGGL(k_span_partial, dim3(16,192), dim3(192), 0, stream, enc, ent_pos, ws);
    hipLaunchKernelGGL(k_span_reduce, dim3(192), dim3(192), 0, stream, ent_pos, projW, projb, ws, out);
    hipLaunchKernelGGL(k_pred_part, dim3(16,8,8), dim3(256), 0, stream, predW1, ws);
    for (int it=0; it<5; ++it){
        float* eS = ws + ((it&1)==0 ? EA_OFF : EB_OFF);
        float* eD = ws + ((it&1)==0 ? EB_OFF : EA_OFF);
        hipLaunchKernelGGL(k_vr_fused, dim3(it==0 ? 264 : 256), dim3(256), 0, stream,
                           VrW1, Vrb1, VrW2, eS, predb1, predW2, predb2, ws, out);
        hipLaunchKernelGGL(k_gate_fused, dim3(256), dim3(384), 0, stream, gateW, gateb, ArW, Arb, Vrb2,
                           eS, eD, ws, (it==4) ? (out+512) : (float*)nullptr);
    }
}